// Round 4
// baseline (418.232 us; speedup 1.0000x reference)
//
#include <hip/hip_runtime.h>

typedef short short8 __attribute__((ext_vector_type(8)));
typedef float f32x4 __attribute__((ext_vector_type(4)));

#define B_   16
#define C_   512
#define N_   1024
#define NH_  8
#define CH_  64
#define G_   32
#define CPG_ 16

__device__ inline float b2f(unsigned int u) {
    union { unsigned int i; float f; } v; v.i = u << 16; return v.f;
}
__device__ inline unsigned short f2b(float f) {
    union { float f; unsigned int i; } v; v.f = f;
    unsigned int r = v.i + 0x7fffu + ((v.i >> 16) & 1u);
    return (unsigned short)(r >> 16);
}
__device__ inline unsigned int pack2(float a, float b) {
    return (unsigned int)f2b(a) | ((unsigned int)f2b(b) << 16);
}
__device__ inline unsigned int asu(float f) {
    union { float f; unsigned int i; } v; v.f = f; return v.i;
}
// truncating bf16 pack: [lo16 = hi16(a) | hi16(b)<<16]
__device__ inline unsigned int packtr(float a, float b) {
    return __builtin_amdgcn_perm(asu(b), asu(a), 0x07060302u);
}

// ---------------- Kernel 0: one-shot fp32->bf16 weight conversion ----------------
__global__ __launch_bounds__(256) void conv_w(const float* __restrict__ qkvw,
                                              const float* __restrict__ projw,
                                              unsigned short* __restrict__ wq,
                                              unsigned short* __restrict__ wp)
{
    const int NQ = 3 * C_ * C_;
    int idx = (blockIdx.x * 256 + threadIdx.x) * 8;
    const float* src; unsigned short* dst; int j;
    if (idx < NQ) { src = qkvw; dst = wq; j = idx; }
    else          { src = projw; dst = wp; j = idx - NQ; }
    float4 u0 = *(const float4*)(src + j);
    float4 u1 = *(const float4*)(src + j + 4);
    uint4 p;
    p.x = pack2(u0.x, u0.y); p.y = pack2(u0.z, u0.w);
    p.z = pack2(u1.x, u1.y); p.w = pack2(u1.z, u1.w);
    *(uint4*)(dst + j) = p;
}

// ---------------- Kernel 1: GroupNorm (fp32 in) + transpose to bf16 [b][n][c] ----------------
__global__ __launch_bounds__(256) void gn_kernel(const float* __restrict__ x,
                                                 const float* __restrict__ nw,
                                                 const float* __restrict__ nb,
                                                 unsigned short* __restrict__ xnT)
{
    int b = blockIdx.x >> 5, g = blockIdx.x & 31;
    int t = threadIdx.x;
    const float* base = x + ((size_t)(b * C_ + g * CPG_)) * N_;

    float s = 0.f, ss = 0.f;
    for (int it = 0; it < 16; ++it) {
        int idx = (it * 256 + t) * 4;
        float4 u = *(const float4*)(base + idx);
        s  += u.x + u.y + u.z + u.w;
        ss += u.x * u.x + u.y * u.y + u.z * u.z + u.w * u.w;
    }
#pragma unroll
    for (int off = 1; off < 64; off <<= 1) {
        s  += __shfl_xor(s, off);
        ss += __shfl_xor(ss, off);
    }
    __shared__ float red[8];
    int wv = t >> 6;
    if ((t & 63) == 0) { red[wv * 2] = s; red[wv * 2 + 1] = ss; }
    __syncthreads();
    s  = red[0] + red[2] + red[4] + red[6];
    ss = red[1] + red[3] + red[5] + red[7];
    float mean = s * (1.f / 16384.f);
    float var  = ss * (1.f / 16384.f) - mean * mean;
    float rstd = rsqrtf(var + 1e-5f);

    int cl = t >> 4, nn4 = (t & 15) * 4;
    float sc = nw[g * CPG_ + cl] * rstd;
    float sh = nb[g * CPG_ + cl] - mean * sc;
    int nlB = t >> 2, c4 = (t & 3) * 4;

    __shared__ unsigned short T[64 * 17];
    for (int ch = 0; ch < 16; ++ch) {
        int n0 = ch * 64;
        float4 u = *(const float4*)(base + (size_t)cl * N_ + n0 + nn4);
        T[(nn4 + 0) * 17 + cl] = f2b(u.x * sc + sh);
        T[(nn4 + 1) * 17 + cl] = f2b(u.y * sc + sh);
        T[(nn4 + 2) * 17 + cl] = f2b(u.z * sc + sh);
        T[(nn4 + 3) * 17 + cl] = f2b(u.w * sc + sh);
        __syncthreads();
        ushort4 o;
        o.x = T[nlB * 17 + c4 + 0];
        o.y = T[nlB * 17 + c4 + 1];
        o.z = T[nlB * 17 + c4 + 2];
        o.w = T[nlB * 17 + c4 + 3];
        *(ushort4*)(xnT + ((size_t)(b * N_ + n0 + nlB)) * C_ + g * CPG_ + c4) = o;
        __syncthreads();
    }
}

// ---------------- Kernel 2: QKV GEMM (bf16 W), M=1536,N=1024,K=512 ----------------
__global__ __launch_bounds__(256) void qkv_kernel(const unsigned short* __restrict__ w,
                                                  const float* __restrict__ bias,
                                                  const unsigned short* __restrict__ xnT,
                                                  unsigned short* __restrict__ qT,
                                                  unsigned short* __restrict__ kT,
                                                  unsigned short* __restrict__ vv)
{
    const int LDA = 40;
    __shared__ unsigned short Als[128 * 40], Bls[128 * 40];
    int t = threadIdx.x;
    int n0 = blockIdx.x * 128, m0 = blockIdx.y * 128, b = blockIdx.z;
    int lane = t & 63, wv = t >> 6;
    int l = lane & 15, qd = lane >> 4;
    int wm = (wv >> 1) * 64, wn = (wv & 1) * 64;
    f32x4 acc[4][4] = {};
    const unsigned short* Bbase = xnT + ((size_t)(b * N_ + n0)) * C_;

    for (int kk = 0; kk < 16; ++kk) {
#pragma unroll
        for (int s_ = 0; s_ < 2; ++s_) {
            int idx = s_ * 256 + t;
            int row = idx >> 2, c8 = (idx & 3) * 8;
            *(uint4*)&Als[row * LDA + c8] = *(const uint4*)(w + (size_t)(m0 + row) * C_ + kk * 32 + c8);
            *(uint4*)&Bls[row * LDA + c8] = *(const uint4*)(Bbase + (size_t)row * C_ + kk * 32 + c8);
        }
        __syncthreads();
        short8 aF[4], bF[4];
#pragma unroll
        for (int i = 0; i < 4; ++i) {
            aF[i] = *(const short8*)&Als[(wm + i * 16 + l) * LDA + qd * 8];
            bF[i] = *(const short8*)&Bls[(wn + i * 16 + l) * LDA + qd * 8];
        }
#pragma unroll
        for (int mt = 0; mt < 4; ++mt)
#pragma unroll
            for (int nt = 0; nt < 4; ++nt)
                acc[mt][nt] = __builtin_amdgcn_mfma_f32_16x16x32_bf16(aF[mt], bF[nt], acc[mt][nt], 0, 0, 0);
        __syncthreads();
    }

    int o_base = m0 + wm;          // multiple of 64
    int sec = o_base >> 9;         // 0:q 1:k 2:v
    int oc = o_base & 511;
    int h = oc >> 6;
    float bv[4][4];
#pragma unroll
    for (int mt = 0; mt < 4; ++mt)
#pragma unroll
        for (int r = 0; r < 4; ++r)
            bv[mt][r] = bias[o_base + mt * 16 + qd * 4 + r];

    if (sec < 2) {
        unsigned short* dst = (sec == 0) ? qT : kT;
        // fold softmax scale (1/8) and log2(e) into q so attention uses raw exp2
        float scl = (sec == 0) ? (0.125f * 1.44269504f) : 1.0f;
#pragma unroll
        for (int mt = 0; mt < 4; ++mt)
#pragma unroll
            for (int nt = 0; nt < 4; ++nt) {
                int n = n0 + wn + nt * 16 + l;
                ushort4 o;
                o.x = f2b((acc[mt][nt][0] + bv[mt][0]) * scl);
                o.y = f2b((acc[mt][nt][1] + bv[mt][1]) * scl);
                o.z = f2b((acc[mt][nt][2] + bv[mt][2]) * scl);
                o.w = f2b((acc[mt][nt][3] + bv[mt][3]) * scl);
                *(ushort4*)(dst + ((size_t)(b * NH_ + h) * N_ + n) * CH_ + mt * 16 + qd * 4) = o;
            }
    } else {
#pragma unroll
        for (int mt = 0; mt < 4; ++mt)
#pragma unroll
            for (int nt = 0; nt < 4; ++nt) {
                int n = n0 + wn + nt * 16 + l;
#pragma unroll
                for (int r = 0; r < 4; ++r) {
                    int ch = mt * 16 + qd * 4 + r;
                    vv[((size_t)(b * NH_ + h) * CH_ + ch) * N_ + n] = f2b(acc[mt][nt][r] + bv[mt][r]);
                }
            }
    }
}

// ---------------- Kernel 3: barrier-free attention. Wave owns ONE 16-col i-tile. ----------------
// S^T = K·Q^T (C-layout: row=j, col=i=l). p=exp2(S') (logits bounded, no max needed).
// P^T -> B-frag via shuffles, O^T[ch][i] accumulated in C-layout. Zero LDS, zero barriers.
__global__ __launch_bounds__(256, 8) void attn_kernel(const unsigned short* __restrict__ qT,
                                                      const unsigned short* __restrict__ kT,
                                                      const unsigned short* __restrict__ vv,
                                                      unsigned short* __restrict__ at)
{
    int t = threadIdx.x, lane = t & 63, wv = t >> 6;
    int l = lane & 15, qd = lane >> 4;
    int i0 = blockIdx.x * 64 + wv * 16;       // this wave's single i-tile
    int h = blockIdx.y, b = blockIdx.z;
    const size_t hoff = (size_t)(b * NH_ + h) * (size_t)N_ * CH_;
    const unsigned short* qbase = qT + hoff;
    const unsigned short* kbase = kT + hoff;
    const unsigned short* vbase = vv + hoff;

    // resident Q B-fragment: B[k=ch][n=i]: lane reads Q[i0+l][ks*32+qd*8 ..+8]
    short8 qF[2];
#pragma unroll
    for (int ks = 0; ks < 2; ++ks)
        qF[ks] = *(const short8*)(qbase + (size_t)(i0 + l) * CH_ + ks * 32 + qd * 8);

    f32x4 Oa[4] = {};       // O^T[cht]: row=ch=cht*16+qd*4+r, col=i=l
    float lsum = 0.f;       // per-lane partial softmax denom (col i=l)

    int la0 = (qd & 1) * 32 + l;   // shuffle src lane (low 4 k), +16 for high 4
    int la1 = la0 + 16;

#pragma unroll 2
    for (int jb = 0; jb < 32; ++jb) {
        int j0 = jb * 32;
        // ---- K A-frags (A[m=j][k=ch]) + S^T MFMA ----
        short8 kA[2][2];
#pragma unroll
        for (int jt = 0; jt < 2; ++jt)
#pragma unroll
            for (int ks = 0; ks < 2; ++ks)
                kA[jt][ks] = *(const short8*)(kbase + (size_t)(j0 + jt * 16 + l) * CH_ + ks * 32 + qd * 8);
        f32x4 Sa[2] = {};
#pragma unroll
        for (int jt = 0; jt < 2; ++jt)
#pragma unroll
            for (int ks = 0; ks < 2; ++ks)
                Sa[jt] = __builtin_amdgcn_mfma_f32_16x16x32_bf16(kA[jt][ks], qF[ks], Sa[jt], 0, 0, 0);
        // ---- p = exp2(S'), accumulate denom, pack to bf16 pairs ----
        unsigned int pk[2][2];   // [jt][pair]
#pragma unroll
        for (int jt = 0; jt < 2; ++jt) {
            float p0 = __builtin_amdgcn_exp2f(Sa[jt][0]);
            float p1 = __builtin_amdgcn_exp2f(Sa[jt][1]);
            float p2 = __builtin_amdgcn_exp2f(Sa[jt][2]);
            float p3 = __builtin_amdgcn_exp2f(Sa[jt][3]);
            lsum += (p0 + p1) + (p2 + p3);
            pk[jt][0] = packtr(p0, p1);
            pk[jt][1] = packtr(p2, p3);
        }
        // ---- build P^T B-frag in-register (B[k=j][n=i]) ----
        union { short8 s; unsigned int u[4]; } fb;
        {
            unsigned int a0 = (unsigned int)__shfl((int)pk[0][0], la0);
            unsigned int b0 = (unsigned int)__shfl((int)pk[1][0], la0);
            fb.u[0] = (qd < 2) ? a0 : b0;
            unsigned int a1 = (unsigned int)__shfl((int)pk[0][1], la0);
            unsigned int b1 = (unsigned int)__shfl((int)pk[1][1], la0);
            fb.u[1] = (qd < 2) ? a1 : b1;
            unsigned int a2 = (unsigned int)__shfl((int)pk[0][0], la1);
            unsigned int b2 = (unsigned int)__shfl((int)pk[1][0], la1);
            fb.u[2] = (qd < 2) ? a2 : b2;
            unsigned int a3 = (unsigned int)__shfl((int)pk[0][1], la1);
            unsigned int b3 = (unsigned int)__shfl((int)pk[1][1], la1);
            fb.u[3] = (qd < 2) ? a3 : b3;
        }
        // ---- V A-frags (A[m=ch][k=j]) + PV MFMA ----
        short8 vA[4];
#pragma unroll
        for (int cht = 0; cht < 4; ++cht)
            vA[cht] = *(const short8*)(vbase + (size_t)(cht * 16 + l) * N_ + j0 + qd * 8);
#pragma unroll
        for (int cht = 0; cht < 4; ++cht)
            Oa[cht] = __builtin_amdgcn_mfma_f32_16x16x32_bf16(vA[cht], fb.s, Oa[cht], 0, 0, 0);
    }

    // ---- epilogue: finish denom across quad groups, scale, store [b][n][c] ----
    float lt = lsum;
    lt += __shfl_xor(lt, 16);
    lt += __shfl_xor(lt, 32);
    float inv = 1.0f / lt;
    int i = i0 + l;
    unsigned short* dst = at + ((size_t)(b * N_ + i)) * C_ + h * CH_;
#pragma unroll
    for (int cht = 0; cht < 4; ++cht) {
        ushort4 o;
        o.x = f2b(Oa[cht][0] * inv);
        o.y = f2b(Oa[cht][1] * inv);
        o.z = f2b(Oa[cht][2] * inv);
        o.w = f2b(Oa[cht][3] * inv);
        *(ushort4*)(dst + cht * 16 + qd * 4) = o;
    }
}

// ---------------- Kernel 4: proj GEMM (bf16 W) + bias + fp32 residual -> fp32 out ----------------
__global__ __launch_bounds__(256) void proj_kernel(const unsigned short* __restrict__ w,
                                                   const float* __restrict__ bias,
                                                   const unsigned short* __restrict__ at,
                                                   const float* __restrict__ x,
                                                   float* __restrict__ out)
{
    const int LDA = 40;
    __shared__ unsigned short Als[128 * 40], Bls[128 * 40];
    int t = threadIdx.x;
    int n0 = blockIdx.x * 128, m0 = blockIdx.y * 128, b = blockIdx.z;
    int lane = t & 63, wv = t >> 6;
    int l = lane & 15, qd = lane >> 4;
    int wm = (wv >> 1) * 64, wn = (wv & 1) * 64;
    f32x4 acc[4][4] = {};
    const unsigned short* Bbase = at + ((size_t)(b * N_ + n0)) * C_;

    for (int kk = 0; kk < 16; ++kk) {
#pragma unroll
        for (int s_ = 0; s_ < 2; ++s_) {
            int idx = s_ * 256 + t;
            int row = idx >> 2, c8 = (idx & 3) * 8;
            *(uint4*)&Als[row * LDA + c8] = *(const uint4*)(w + (size_t)(m0 + row) * C_ + kk * 32 + c8);
            *(uint4*)&Bls[row * LDA + c8] = *(const uint4*)(Bbase + (size_t)row * C_ + kk * 32 + c8);
        }
        __syncthreads();
        short8 aF[4], bF[4];
#pragma unroll
        for (int i = 0; i < 4; ++i) {
            aF[i] = *(const short8*)&Als[(wm + i * 16 + l) * LDA + qd * 8];
            bF[i] = *(const short8*)&Bls[(wn + i * 16 + l) * LDA + qd * 8];
        }
#pragma unroll
        for (int mt = 0; mt < 4; ++mt)
#pragma unroll
            for (int nt = 0; nt < 4; ++nt)
                acc[mt][nt] = __builtin_amdgcn_mfma_f32_16x16x32_bf16(aF[mt], bF[nt], acc[mt][nt], 0, 0, 0);
        __syncthreads();
    }

    float bv[4][4];
#pragma unroll
    for (int mt = 0; mt < 4; ++mt)
#pragma unroll
        for (int r = 0; r < 4; ++r)
            bv[mt][r] = bias[m0 + wm + mt * 16 + qd * 4 + r];

#pragma unroll
    for (int mt = 0; mt < 4; ++mt)
#pragma unroll
        for (int nt = 0; nt < 4; ++nt) {
            int n = n0 + wn + nt * 16 + l;
#pragma unroll
            for (int r = 0; r < 4; ++r) {
                int o = m0 + wm + mt * 16 + qd * 4 + r;
                size_t idx = ((size_t)b * C_ + o) * N_ + n;
                out[idx] = acc[mt][nt][r] + bv[mt][r] + x[idx];
            }
        }
}

extern "C" void kernel_launch(void* const* d_in, const int* in_sizes, int n_in,
                              void* d_out, int out_size, void* d_ws, size_t ws_size,
                              hipStream_t stream) {
    const float* x     = (const float*)d_in[0];
    const float* nw    = (const float*)d_in[1];
    const float* nb    = (const float*)d_in[2];
    const float* qkvw  = (const float*)d_in[3];
    const float* qkvb  = (const float*)d_in[4];
    const float* projw = (const float*)d_in[5];
    const float* projb = (const float*)d_in[6];
    float* out = (float*)d_out;
    char* ws = (char*)d_ws;
    const size_t SZ = (size_t)B_ * N_ * C_ * 2;   // 16 MiB per bf16 [b][n][c] tensor
    unsigned short* xnT = (unsigned short*)(ws);
    unsigned short* qTp = (unsigned short*)(ws + SZ);
    unsigned short* kTp = (unsigned short*)(ws + 2 * SZ);
    unsigned short* vp  = (unsigned short*)(ws + 3 * SZ);
    unsigned short* atp = (unsigned short*)(ws);          // alias xnT: dead after qkv_kernel
    unsigned short* wq  = (unsigned short*)(ws + 4 * SZ); // bf16 qkv_w (1.5 MiB)
    unsigned short* wp  = (unsigned short*)(ws + 4 * SZ + (size_t)3 * C_ * C_ * 2); // bf16 proj_w

    hipLaunchKernelGGL(conv_w,      dim3(512), dim3(256), 0, stream, qkvw, projw, wq, wp);
    hipLaunchKernelGGL(gn_kernel,   dim3(B_ * G_), dim3(256), 0, stream, x, nw, nb, xnT);
    hipLaunchKernelGGL(qkv_kernel,  dim3(8, 12, B_), dim3(256), 0, stream, wq, qkvb, xnT, qTp, kTp, vp);
    hipLaunchKernelGGL(attn_kernel, dim3(16, NH_, B_), dim3(256), 0, stream, qTp, kTp, vp, atp);
    hipLaunchKernelGGL(proj_kernel, dim3(8, 4, B_), dim3(256), 0, stream, wp, projb, atp, x, out);
}

// Round 5
// 227.338 us; speedup vs baseline: 1.8397x; 1.8397x over previous
//
#include <hip/hip_runtime.h>

typedef short short8 __attribute__((ext_vector_type(8)));
typedef float f32x4 __attribute__((ext_vector_type(4)));

#define B_   16
#define C_   512
#define N_   1024
#define NH_  8
#define CH_  64
#define G_   32
#define CPG_ 16

__device__ inline float b2f(unsigned int u) {
    union { unsigned int i; float f; } v; v.i = u << 16; return v.f;
}
__device__ inline unsigned short f2b(float f) {
    union { float f; unsigned int i; } v; v.f = f;
    unsigned int r = v.i + 0x7fffu + ((v.i >> 16) & 1u);
    return (unsigned short)(r >> 16);
}
__device__ inline unsigned int pack2(float a, float b) {
    return (unsigned int)f2b(a) | ((unsigned int)f2b(b) << 16);
}
__device__ inline unsigned int asu(float f) {
    union { float f; unsigned int i; } v; v.f = f; return v.i;
}
// truncating bf16 pack: [lo16 = hi16(a) | hi16(b)<<16]
__device__ inline unsigned int packtr(float a, float b) {
    return __builtin_amdgcn_perm(asu(b), asu(a), 0x07060302u);
}

// ---------------- Kernel 0: one-shot fp32->bf16 weight conversion ----------------
__global__ __launch_bounds__(256) void conv_w(const float* __restrict__ qkvw,
                                              const float* __restrict__ projw,
                                              unsigned short* __restrict__ wq,
                                              unsigned short* __restrict__ wp)
{
    const int NQ = 3 * C_ * C_;
    int idx = (blockIdx.x * 256 + threadIdx.x) * 8;
    const float* src; unsigned short* dst; int j;
    if (idx < NQ) { src = qkvw; dst = wq; j = idx; }
    else          { src = projw; dst = wp; j = idx - NQ; }
    float4 u0 = *(const float4*)(src + j);
    float4 u1 = *(const float4*)(src + j + 4);
    uint4 p;
    p.x = pack2(u0.x, u0.y); p.y = pack2(u0.z, u0.w);
    p.z = pack2(u1.x, u1.y); p.w = pack2(u1.z, u1.w);
    *(uint4*)(dst + j) = p;
}

// ---------------- Kernel 1: GroupNorm (fp32 in) + transpose to bf16 [b][n][c] ----------------
__global__ __launch_bounds__(256) void gn_kernel(const float* __restrict__ x,
                                                 const float* __restrict__ nw,
                                                 const float* __restrict__ nb,
                                                 unsigned short* __restrict__ xnT)
{
    int b = blockIdx.x >> 5, g = blockIdx.x & 31;
    int t = threadIdx.x;
    const float* base = x + ((size_t)(b * C_ + g * CPG_)) * N_;

    float s = 0.f, ss = 0.f;
    for (int it = 0; it < 16; ++it) {
        int idx = (it * 256 + t) * 4;
        float4 u = *(const float4*)(base + idx);
        s  += u.x + u.y + u.z + u.w;
        ss += u.x * u.x + u.y * u.y + u.z * u.z + u.w * u.w;
    }
#pragma unroll
    for (int off = 1; off < 64; off <<= 1) {
        s  += __shfl_xor(s, off);
        ss += __shfl_xor(ss, off);
    }
    __shared__ float red[8];
    int wv = t >> 6;
    if ((t & 63) == 0) { red[wv * 2] = s; red[wv * 2 + 1] = ss; }
    __syncthreads();
    s  = red[0] + red[2] + red[4] + red[6];
    ss = red[1] + red[3] + red[5] + red[7];
    float mean = s * (1.f / 16384.f);
    float var  = ss * (1.f / 16384.f) - mean * mean;
    float rstd = rsqrtf(var + 1e-5f);

    int cl = t >> 4, nn4 = (t & 15) * 4;
    float sc = nw[g * CPG_ + cl] * rstd;
    float sh = nb[g * CPG_ + cl] - mean * sc;
    int nlB = t >> 2, c4 = (t & 3) * 4;

    __shared__ unsigned short T[64 * 17];
    for (int ch = 0; ch < 16; ++ch) {
        int n0 = ch * 64;
        float4 u = *(const float4*)(base + (size_t)cl * N_ + n0 + nn4);
        T[(nn4 + 0) * 17 + cl] = f2b(u.x * sc + sh);
        T[(nn4 + 1) * 17 + cl] = f2b(u.y * sc + sh);
        T[(nn4 + 2) * 17 + cl] = f2b(u.z * sc + sh);
        T[(nn4 + 3) * 17 + cl] = f2b(u.w * sc + sh);
        __syncthreads();
        ushort4 o;
        o.x = T[nlB * 17 + c4 + 0];
        o.y = T[nlB * 17 + c4 + 1];
        o.z = T[nlB * 17 + c4 + 2];
        o.w = T[nlB * 17 + c4 + 3];
        *(ushort4*)(xnT + ((size_t)(b * N_ + n0 + nlB)) * C_ + g * CPG_ + c4) = o;
        __syncthreads();
    }
}

// ---------------- Kernel 2: QKV GEMM (bf16 W), M=1536,N=1024,K=512 ----------------
__global__ __launch_bounds__(256) void qkv_kernel(const unsigned short* __restrict__ w,
                                                  const float* __restrict__ bias,
                                                  const unsigned short* __restrict__ xnT,
                                                  unsigned short* __restrict__ qT,
                                                  unsigned short* __restrict__ kT,
                                                  unsigned short* __restrict__ vv)
{
    const int LDA = 40;
    __shared__ unsigned short Als[128 * 40], Bls[128 * 40];
    int t = threadIdx.x;
    int n0 = blockIdx.x * 128, m0 = blockIdx.y * 128, b = blockIdx.z;
    int lane = t & 63, wv = t >> 6;
    int l = lane & 15, qd = lane >> 4;
    int wm = (wv >> 1) * 64, wn = (wv & 1) * 64;
    f32x4 acc[4][4] = {};
    const unsigned short* Bbase = xnT + ((size_t)(b * N_ + n0)) * C_;

    for (int kk = 0; kk < 16; ++kk) {
#pragma unroll
        for (int s_ = 0; s_ < 2; ++s_) {
            int idx = s_ * 256 + t;
            int row = idx >> 2, c8 = (idx & 3) * 8;
            *(uint4*)&Als[row * LDA + c8] = *(const uint4*)(w + (size_t)(m0 + row) * C_ + kk * 32 + c8);
            *(uint4*)&Bls[row * LDA + c8] = *(const uint4*)(Bbase + (size_t)row * C_ + kk * 32 + c8);
        }
        __syncthreads();
        short8 aF[4], bF[4];
#pragma unroll
        for (int i = 0; i < 4; ++i) {
            aF[i] = *(const short8*)&Als[(wm + i * 16 + l) * LDA + qd * 8];
            bF[i] = *(const short8*)&Bls[(wn + i * 16 + l) * LDA + qd * 8];
        }
#pragma unroll
        for (int mt = 0; mt < 4; ++mt)
#pragma unroll
            for (int nt = 0; nt < 4; ++nt)
                acc[mt][nt] = __builtin_amdgcn_mfma_f32_16x16x32_bf16(aF[mt], bF[nt], acc[mt][nt], 0, 0, 0);
        __syncthreads();
    }

    int o_base = m0 + wm;          // multiple of 64
    int sec = o_base >> 9;         // 0:q 1:k 2:v
    int oc = o_base & 511;
    int h = oc >> 6;
    float bv[4][4];
#pragma unroll
    for (int mt = 0; mt < 4; ++mt)
#pragma unroll
        for (int r = 0; r < 4; ++r)
            bv[mt][r] = bias[o_base + mt * 16 + qd * 4 + r];

    if (sec < 2) {
        unsigned short* dst = (sec == 0) ? qT : kT;
        // fold softmax scale (1/8) and log2(e) into q so attention uses raw exp2
        float scl = (sec == 0) ? (0.125f * 1.44269504f) : 1.0f;
#pragma unroll
        for (int mt = 0; mt < 4; ++mt)
#pragma unroll
            for (int nt = 0; nt < 4; ++nt) {
                int n = n0 + wn + nt * 16 + l;
                ushort4 o;
                o.x = f2b((acc[mt][nt][0] + bv[mt][0]) * scl);
                o.y = f2b((acc[mt][nt][1] + bv[mt][1]) * scl);
                o.z = f2b((acc[mt][nt][2] + bv[mt][2]) * scl);
                o.w = f2b((acc[mt][nt][3] + bv[mt][3]) * scl);
                *(ushort4*)(dst + ((size_t)(b * NH_ + h) * N_ + n) * CH_ + mt * 16 + qd * 4) = o;
            }
    } else {
#pragma unroll
        for (int mt = 0; mt < 4; ++mt)
#pragma unroll
            for (int nt = 0; nt < 4; ++nt) {
                int n = n0 + wn + nt * 16 + l;
#pragma unroll
                for (int r = 0; r < 4; ++r) {
                    int ch = mt * 16 + qd * 4 + r;
                    vv[((size_t)(b * NH_ + h) * CH_ + ch) * N_ + n] = f2b(acc[mt][nt][r] + bv[mt][r]);
                }
            }
    }
}

// ---------------- Kernel 3: attention with double-buffered LDS K/V staging ----------------
// Block = 4 waves x 32 i-cols = 128 i. j swept in 16 tiles of 64 (one barrier per tile).
// K/V staged via coalesced dwordx4 global loads -> XOR-swizzled LDS (conflict-free b128 reads).
// S^T = K.Q^T in C-layout, per-lane softmax denom, in-register P^T via shuffles, O^T accumulate.
__global__ __launch_bounds__(256, 4) void attn_kernel(const unsigned short* __restrict__ qT,
                                                      const unsigned short* __restrict__ kT,
                                                      const unsigned short* __restrict__ vv,
                                                      unsigned short* __restrict__ at)
{
    __shared__ unsigned short Ks[2][4096];   // [64 j][64 ch], 16B-block swizzled
    __shared__ unsigned short Vs[2][4096];   // [64 ch][64 j], 16B-block swizzled

    int t = threadIdx.x, lane = t & 63, wv = t >> 6;
    int l = lane & 15, qd = lane >> 4;
    int blk = blockIdx.x;
    int ibk = blk >> 7;           // 0..7 (i-block)  -- bh in low bits => same (b,h) shares XCD
    int bh  = blk & 127;
    int h = bh & 7, b = bh >> 3;
    int i0 = ibk * 128 + wv * 32;
    const size_t hoff = (size_t)bh * (size_t)N_ * CH_;
    const unsigned short* qbase = qT + hoff;
    const unsigned short* kbase = kT + hoff;
    const unsigned short* vbase = vv + hoff;

    // resident Q B-fragments: B[k=ch][n=i]; lane reads Q[i0+it*16+l][ks*32+qd*8 ..+8]
    short8 qF[2][2];
#pragma unroll
    for (int it = 0; it < 2; ++it)
#pragma unroll
        for (int ks = 0; ks < 2; ++ks)
            qF[it][ks] = *(const short8*)(qbase + (size_t)(i0 + it * 16 + l) * CH_ + ks * 32 + qd * 8);

    // staging geometry: thread t handles row (t>>2), 16 elems at (t&3)*16
    int srow = t >> 2, sc16 = (t & 3) * 16;
    int sw = srow & 7, bb = (t & 3) * 2;
    int d0 = srow * 64 + ((bb ^ sw) * 8);
    int d1 = srow * 64 + (((bb + 1) ^ sw) * 8);
    const unsigned short* kSrc = kbase + (size_t)srow * CH_ + sc16;   // + tile*4096
    const unsigned short* vSrc = vbase + (size_t)srow * N_ + sc16;    // + tile*64

    f32x4 Oa[4][2] = {};        // O^T[cht][it]: row=ch=cht*16+qd*4+r, col=i=l
    float lsum[2] = {0.f, 0.f};
    int la0 = (qd & 1) * 32 + l;
    int la1 = la0 + 16;
    int swl = l & 7;

    uint4 ku0, ku1, vu0, vu1;
    // prologue: tile 0 -> LDS buf0; tile 1 -> regs
    {
        const uint4* kp = (const uint4*)(kSrc);
        ku0 = kp[0]; ku1 = kp[1];
        const uint4* vp2 = (const uint4*)(vSrc);
        vu0 = vp2[0]; vu1 = vp2[1];
        *(uint4*)&Ks[0][d0] = ku0; *(uint4*)&Ks[0][d1] = ku1;
        *(uint4*)&Vs[0][d0] = vu0; *(uint4*)&Vs[0][d1] = vu1;
        kp  = (const uint4*)(kSrc + 4096);
        ku0 = kp[0]; ku1 = kp[1];
        vp2 = (const uint4*)(vSrc + 64);
        vu0 = vp2[0]; vu1 = vp2[1];
    }

    for (int tile = 0; tile < 16; ++tile) {
        __syncthreads();
        if (tile < 15) {
            unsigned short* Kw = Ks[(tile + 1) & 1];
            unsigned short* Vw = Vs[(tile + 1) & 1];
            *(uint4*)&Kw[d0] = ku0; *(uint4*)&Kw[d1] = ku1;
            *(uint4*)&Vw[d0] = vu0; *(uint4*)&Vw[d1] = vu1;
            if (tile < 14) {
                const uint4* kp = (const uint4*)(kSrc + (size_t)(tile + 2) * 4096);
                ku0 = kp[0]; ku1 = kp[1];
                const uint4* vp2 = (const uint4*)(vSrc + (size_t)(tile + 2) * 64);
                vu0 = vp2[0]; vu1 = vp2[1];
            }
        }
        const unsigned short* Kb = Ks[tile & 1];
        const unsigned short* Vb = Vs[tile & 1];
#pragma unroll
        for (int jb = 0; jb < 2; ++jb) {
            // ---- K A-frags from LDS + S^T MFMA ----
            short8 kA[2][2];
#pragma unroll
            for (int jt = 0; jt < 2; ++jt)
#pragma unroll
                for (int ks = 0; ks < 2; ++ks)
                    kA[jt][ks] = *(const short8*)&Kb[(jb * 32 + jt * 16 + l) * 64 + (((ks * 4 + qd) ^ swl) * 8)];
            f32x4 Sa[2][2] = {};
#pragma unroll
            for (int jt = 0; jt < 2; ++jt)
#pragma unroll
                for (int it = 0; it < 2; ++it)
#pragma unroll
                    for (int ks = 0; ks < 2; ++ks)
                        Sa[jt][it] = __builtin_amdgcn_mfma_f32_16x16x32_bf16(kA[jt][ks], qF[it][ks], Sa[jt][it], 0, 0, 0);
            // ---- p = exp2(S'), accumulate denom, pack ----
            unsigned int pk[2][2][2];
#pragma unroll
            for (int jt = 0; jt < 2; ++jt)
#pragma unroll
                for (int it = 0; it < 2; ++it) {
                    float p0 = __builtin_amdgcn_exp2f(Sa[jt][it][0]);
                    float p1 = __builtin_amdgcn_exp2f(Sa[jt][it][1]);
                    float p2 = __builtin_amdgcn_exp2f(Sa[jt][it][2]);
                    float p3 = __builtin_amdgcn_exp2f(Sa[jt][it][3]);
                    lsum[it] += (p0 + p1) + (p2 + p3);
                    pk[jt][it][0] = packtr(p0, p1);
                    pk[jt][it][1] = packtr(p2, p3);
                }
            // ---- P^T B-frags in-register ----
            short8 bP[2];
#pragma unroll
            for (int it = 0; it < 2; ++it) {
                union { short8 s; unsigned int u[4]; } fb;
                unsigned int a0 = (unsigned int)__shfl((int)pk[0][it][0], la0);
                unsigned int b0 = (unsigned int)__shfl((int)pk[1][it][0], la0);
                fb.u[0] = (qd < 2) ? a0 : b0;
                unsigned int a1 = (unsigned int)__shfl((int)pk[0][it][1], la0);
                unsigned int b1 = (unsigned int)__shfl((int)pk[1][it][1], la0);
                fb.u[1] = (qd < 2) ? a1 : b1;
                unsigned int a2 = (unsigned int)__shfl((int)pk[0][it][0], la1);
                unsigned int b2 = (unsigned int)__shfl((int)pk[1][it][0], la1);
                fb.u[2] = (qd < 2) ? a2 : b2;
                unsigned int a3 = (unsigned int)__shfl((int)pk[0][it][1], la1);
                unsigned int b3 = (unsigned int)__shfl((int)pk[1][it][1], la1);
                fb.u[3] = (qd < 2) ? a3 : b3;
                bP[it] = fb.s;
            }
            // ---- V A-frags from LDS + PV MFMA ----
            short8 vA[4];
#pragma unroll
            for (int cht = 0; cht < 4; ++cht)
                vA[cht] = *(const short8*)&Vb[(cht * 16 + l) * 64 + (((jb * 4 + qd) ^ swl) * 8)];
#pragma unroll
            for (int cht = 0; cht < 4; ++cht)
#pragma unroll
                for (int it = 0; it < 2; ++it)
                    Oa[cht][it] = __builtin_amdgcn_mfma_f32_16x16x32_bf16(vA[cht], bP[it], Oa[cht][it], 0, 0, 0);
        }
    }

    // ---- epilogue: finish denom across quad groups, scale, store [b][n][c] ----
#pragma unroll
    for (int it = 0; it < 2; ++it) {
        float lt = lsum[it];
        lt += __shfl_xor(lt, 16);
        lt += __shfl_xor(lt, 32);
        float inv = 1.0f / lt;
        int i = i0 + it * 16 + l;
        unsigned short* dst = at + ((size_t)(b * N_ + i)) * C_ + h * CH_;
#pragma unroll
        for (int cht = 0; cht < 4; ++cht) {
            ushort4 o;
            o.x = f2b(Oa[cht][it][0] * inv);
            o.y = f2b(Oa[cht][it][1] * inv);
            o.z = f2b(Oa[cht][it][2] * inv);
            o.w = f2b(Oa[cht][it][3] * inv);
            *(ushort4*)(dst + cht * 16 + qd * 4) = o;
        }
    }
}

// ---------------- Kernel 4: proj GEMM (bf16 W) + bias + fp32 residual -> fp32 out ----------------
__global__ __launch_bounds__(256) void proj_kernel(const unsigned short* __restrict__ w,
                                                   const float* __restrict__ bias,
                                                   const unsigned short* __restrict__ at,
                                                   const float* __restrict__ x,
                                                   float* __restrict__ out)
{
    const int LDA = 40;
    __shared__ unsigned short Als[128 * 40], Bls[128 * 40];
    int t = threadIdx.x;
    int n0 = blockIdx.x * 128, m0 = blockIdx.y * 128, b = blockIdx.z;
    int lane = t & 63, wv = t >> 6;
    int l = lane & 15, qd = lane >> 4;
    int wm = (wv >> 1) * 64, wn = (wv & 1) * 64;
    f32x4 acc[4][4] = {};
    const unsigned short* Bbase = at + ((size_t)(b * N_ + n0)) * C_;

    for (int kk = 0; kk < 16; ++kk) {
#pragma unroll
        for (int s_ = 0; s_ < 2; ++s_) {
            int idx = s_ * 256 + t;
            int row = idx >> 2, c8 = (idx & 3) * 8;
            *(uint4*)&Als[row * LDA + c8] = *(const uint4*)(w + (size_t)(m0 + row) * C_ + kk * 32 + c8);
            *(uint4*)&Bls[row * LDA + c8] = *(const uint4*)(Bbase + (size_t)row * C_ + kk * 32 + c8);
        }
        __syncthreads();
        short8 aF[4], bF[4];
#pragma unroll
        for (int i = 0; i < 4; ++i) {
            aF[i] = *(const short8*)&Als[(wm + i * 16 + l) * LDA + qd * 8];
            bF[i] = *(const short8*)&Bls[(wn + i * 16 + l) * LDA + qd * 8];
        }
#pragma unroll
        for (int mt = 0; mt < 4; ++mt)
#pragma unroll
            for (int nt = 0; nt < 4; ++nt)
                acc[mt][nt] = __builtin_amdgcn_mfma_f32_16x16x32_bf16(aF[mt], bF[nt], acc[mt][nt], 0, 0, 0);
        __syncthreads();
    }

    float bv[4][4];
#pragma unroll
    for (int mt = 0; mt < 4; ++mt)
#pragma unroll
        for (int r = 0; r < 4; ++r)
            bv[mt][r] = bias[m0 + wm + mt * 16 + qd * 4 + r];

#pragma unroll
    for (int mt = 0; mt < 4; ++mt)
#pragma unroll
        for (int nt = 0; nt < 4; ++nt) {
            int n = n0 + wn + nt * 16 + l;
#pragma unroll
            for (int r = 0; r < 4; ++r) {
                int o = m0 + wm + mt * 16 + qd * 4 + r;
                size_t idx = ((size_t)b * C_ + o) * N_ + n;
                out[idx] = acc[mt][nt][r] + bv[mt][r] + x[idx];
            }
        }
}

extern "C" void kernel_launch(void* const* d_in, const int* in_sizes, int n_in,
                              void* d_out, int out_size, void* d_ws, size_t ws_size,
                              hipStream_t stream) {
    const float* x     = (const float*)d_in[0];
    const float* nw    = (const float*)d_in[1];
    const float* nb    = (const float*)d_in[2];
    const float* qkvw  = (const float*)d_in[3];
    const float* qkvb  = (const float*)d_in[4];
    const float* projw = (const float*)d_in[5];
    const float* projb = (const float*)d_in[6];
    float* out = (float*)d_out;
    char* ws = (char*)d_ws;
    const size_t SZ = (size_t)B_ * N_ * C_ * 2;   // 16 MiB per bf16 [b][n][c] tensor
    unsigned short* xnT = (unsigned short*)(ws);
    unsigned short* qTp = (unsigned short*)(ws + SZ);
    unsigned short* kTp = (unsigned short*)(ws + 2 * SZ);
    unsigned short* vp  = (unsigned short*)(ws + 3 * SZ);
    unsigned short* atp = (unsigned short*)(ws);          // alias xnT: dead after qkv_kernel
    unsigned short* wq  = (unsigned short*)(ws + 4 * SZ); // bf16 qkv_w (1.5 MiB)
    unsigned short* wp  = (unsigned short*)(ws + 4 * SZ + (size_t)3 * C_ * C_ * 2); // bf16 proj_w

    hipLaunchKernelGGL(conv_w,      dim3(512), dim3(256), 0, stream, qkvw, projw, wq, wp);
    hipLaunchKernelGGL(gn_kernel,   dim3(B_ * G_), dim3(256), 0, stream, x, nw, nb, xnT);
    hipLaunchKernelGGL(qkv_kernel,  dim3(8, 12, B_), dim3(256), 0, stream, wq, qkvb, xnT, qTp, kTp, vp);
    hipLaunchKernelGGL(attn_kernel, dim3(1024), dim3(256), 0, stream, qTp, kTp, vp, atp);
    hipLaunchKernelGGL(proj_kernel, dim3(8, 4, B_), dim3(256), 0, stream, wp, projb, atp, x, out);
}

// Round 6
// 219.068 us; speedup vs baseline: 1.9091x; 1.0378x over previous
//
#include <hip/hip_runtime.h>

typedef short short8 __attribute__((ext_vector_type(8)));
typedef float f32x4 __attribute__((ext_vector_type(4)));

#define B_   16
#define C_   512
#define N_   1024
#define NH_  8
#define CH_  64
#define G_   32
#define CPG_ 16

__device__ inline float b2f(unsigned int u) {
    union { unsigned int i; float f; } v; v.i = u << 16; return v.f;
}
__device__ inline unsigned short f2b(float f) {
    union { float f; unsigned int i; } v; v.f = f;
    unsigned int r = v.i + 0x7fffu + ((v.i >> 16) & 1u);
    return (unsigned short)(r >> 16);
}
__device__ inline unsigned int pack2(float a, float b) {
    return (unsigned int)f2b(a) | ((unsigned int)f2b(b) << 16);
}
__device__ inline unsigned int asu(float f) {
    union { float f; unsigned int i; } v; v.f = f; return v.i;
}
// truncating bf16 pack: [lo16 = hi16(a) | hi16(b)<<16]
__device__ inline unsigned int packtr(float a, float b) {
    return __builtin_amdgcn_perm(asu(b), asu(a), 0x07060302u);
}
// async global->LDS, 16B per lane; LDS dst = wave-uniform base + lane*16
__device__ inline void gload16(const void* g, void* l) {
    __builtin_amdgcn_global_load_lds(
        (const __attribute__((address_space(1))) void*)g,
        (__attribute__((address_space(3))) void*)l, 16, 0, 0);
}

// ---------------- Kernel 1: GroupNorm + transpose (blocks 0-511) | weight conv (512-1023) ----------
__global__ __launch_bounds__(256) void gnconv_kernel(const float* __restrict__ x,
                                                     const float* __restrict__ nw,
                                                     const float* __restrict__ nb,
                                                     unsigned short* __restrict__ xnT,
                                                     const float* __restrict__ qkvw,
                                                     const float* __restrict__ projw,
                                                     unsigned short* __restrict__ wq,
                                                     unsigned short* __restrict__ wp)
{
    __shared__ float red[8];
    __shared__ unsigned short T[64 * 17];
    int t = threadIdx.x;

    if (blockIdx.x >= 512) {
        const int NQ = 3 * C_ * C_;
        int idx = (((int)blockIdx.x - 512) * 256 + t) * 8;
        const float* src; unsigned short* dst; int j;
        if (idx < NQ) { src = qkvw;  dst = wq; j = idx; }
        else          { src = projw; dst = wp; j = idx - NQ; }
        float4 u0 = *(const float4*)(src + j);
        float4 u1 = *(const float4*)(src + j + 4);
        uint4 p;
        p.x = pack2(u0.x, u0.y); p.y = pack2(u0.z, u0.w);
        p.z = pack2(u1.x, u1.y); p.w = pack2(u1.z, u1.w);
        *(uint4*)(dst + j) = p;
        return;
    }

    int b = blockIdx.x >> 5, g = blockIdx.x & 31;
    const float* base = x + ((size_t)(b * C_ + g * CPG_)) * N_;

    float s = 0.f, ss = 0.f;
    for (int it = 0; it < 16; ++it) {
        int idx = (it * 256 + t) * 4;
        float4 u = *(const float4*)(base + idx);
        s  += u.x + u.y + u.z + u.w;
        ss += u.x * u.x + u.y * u.y + u.z * u.z + u.w * u.w;
    }
#pragma unroll
    for (int off = 1; off < 64; off <<= 1) {
        s  += __shfl_xor(s, off);
        ss += __shfl_xor(ss, off);
    }
    int wv = t >> 6;
    if ((t & 63) == 0) { red[wv * 2] = s; red[wv * 2 + 1] = ss; }
    __syncthreads();
    s  = red[0] + red[2] + red[4] + red[6];
    ss = red[1] + red[3] + red[5] + red[7];
    float mean = s * (1.f / 16384.f);
    float var  = ss * (1.f / 16384.f) - mean * mean;
    float rstd = rsqrtf(var + 1e-5f);

    int cl = t >> 4, nn4 = (t & 15) * 4;
    float sc = nw[g * CPG_ + cl] * rstd;
    float sh = nb[g * CPG_ + cl] - mean * sc;
    int nlB = t >> 2, c4 = (t & 3) * 4;

    for (int ch = 0; ch < 16; ++ch) {
        int n0 = ch * 64;
        float4 u = *(const float4*)(base + (size_t)cl * N_ + n0 + nn4);
        T[(nn4 + 0) * 17 + cl] = f2b(u.x * sc + sh);
        T[(nn4 + 1) * 17 + cl] = f2b(u.y * sc + sh);
        T[(nn4 + 2) * 17 + cl] = f2b(u.z * sc + sh);
        T[(nn4 + 3) * 17 + cl] = f2b(u.w * sc + sh);
        __syncthreads();
        ushort4 o;
        o.x = T[nlB * 17 + c4 + 0];
        o.y = T[nlB * 17 + c4 + 1];
        o.z = T[nlB * 17 + c4 + 2];
        o.w = T[nlB * 17 + c4 + 3];
        *(ushort4*)(xnT + ((size_t)(b * N_ + n0 + nlB)) * C_ + g * CPG_ + c4) = o;
        __syncthreads();
    }
}

// ---------------- Kernel 2: QKV GEMM, global_load_lds staging + XOR-swizzled LDS ----------------
__global__ __launch_bounds__(256) void qkv_kernel(const unsigned short* __restrict__ w,
                                                  const float* __restrict__ bias,
                                                  const unsigned short* __restrict__ xnT,
                                                  unsigned short* __restrict__ qT,
                                                  unsigned short* __restrict__ kT,
                                                  unsigned short* __restrict__ vv)
{
    __shared__ unsigned short Als[128 * 32], Bls[128 * 32];
    int t = threadIdx.x;
    int n0 = blockIdx.x * 128, m0 = blockIdx.y * 128, b = blockIdx.z;
    int lane = t & 63, wv = t >> 6;
    int l = lane & 15, qd = lane >> 4;
    int wm = (wv >> 1) * 64, wn = (wv & 1) * 64;
    f32x4 acc[4][4] = {};
    const unsigned short* Bbase = xnT + ((size_t)(b * N_ + n0)) * C_;

    // staging: wave wv covers rows [wv*32, wv*32+32), 2 instrs per matrix
    int lr = lane >> 2, bpos = lane & 3;
    int r0 = wv * 32 + lr, r1 = r0 + 16;
    int c0 = (bpos ^ ((r0 >> 1) & 3)) * 8;
    int c1 = (bpos ^ ((r1 >> 1) & 3)) * 8;
    const unsigned short* gA0 = w + (size_t)(m0 + r0) * C_ + c0;
    const unsigned short* gA1 = w + (size_t)(m0 + r1) * C_ + c1;
    const unsigned short* gB0 = Bbase + (size_t)r0 * C_ + c0;
    const unsigned short* gB1 = Bbase + (size_t)r1 * C_ + c1;
    unsigned short* lA0 = &Als[(wv * 32) * 32];
    unsigned short* lA1 = &Als[(wv * 32 + 16) * 32];
    unsigned short* lB0 = &Bls[(wv * 32) * 32];
    unsigned short* lB1 = &Bls[(wv * 32 + 16) * 32];

    // fragment read offsets (swizzle folded per lane)
    int aoff[4], boff[4];
#pragma unroll
    for (int i = 0; i < 4; ++i) {
        int ra = wm + i * 16 + l;
        aoff[i] = ra * 32 + ((qd ^ ((ra >> 1) & 3)) * 8);
        int rb = wn + i * 16 + l;
        boff[i] = rb * 32 + ((qd ^ ((rb >> 1) & 3)) * 8);
    }

    for (int kk = 0; kk < 16; ++kk) {
        int ko = kk * 32;
        gload16(gA0 + ko, lA0); gload16(gA1 + ko, lA1);
        gload16(gB0 + ko, lB0); gload16(gB1 + ko, lB1);
        __builtin_amdgcn_s_waitcnt(0);
        __syncthreads();
        short8 aF[4], bF[4];
#pragma unroll
        for (int i = 0; i < 4; ++i) {
            aF[i] = *(const short8*)&Als[aoff[i]];
            bF[i] = *(const short8*)&Bls[boff[i]];
        }
#pragma unroll
        for (int mt = 0; mt < 4; ++mt)
#pragma unroll
            for (int nt = 0; nt < 4; ++nt)
                acc[mt][nt] = __builtin_amdgcn_mfma_f32_16x16x32_bf16(aF[mt], bF[nt], acc[mt][nt], 0, 0, 0);
        __syncthreads();
    }

    int o_base = m0 + wm;          // multiple of 64
    int sec = o_base >> 9;         // 0:q 1:k 2:v
    int oc = o_base & 511;
    int h = oc >> 6;
    float bv[4][4];
#pragma unroll
    for (int mt = 0; mt < 4; ++mt)
#pragma unroll
        for (int r = 0; r < 4; ++r)
            bv[mt][r] = bias[o_base + mt * 16 + qd * 4 + r];

    if (sec < 2) {
        unsigned short* dst = (sec == 0) ? qT : kT;
        // fold softmax scale (1/8) and log2(e) into q so attention uses raw exp2
        float scl = (sec == 0) ? (0.125f * 1.44269504f) : 1.0f;
#pragma unroll
        for (int mt = 0; mt < 4; ++mt)
#pragma unroll
            for (int nt = 0; nt < 4; ++nt) {
                int n = n0 + wn + nt * 16 + l;
                ushort4 o;
                o.x = f2b((acc[mt][nt][0] + bv[mt][0]) * scl);
                o.y = f2b((acc[mt][nt][1] + bv[mt][1]) * scl);
                o.z = f2b((acc[mt][nt][2] + bv[mt][2]) * scl);
                o.w = f2b((acc[mt][nt][3] + bv[mt][3]) * scl);
                *(ushort4*)(dst + ((size_t)(b * NH_ + h) * N_ + n) * CH_ + mt * 16 + qd * 4) = o;
            }
    } else {
#pragma unroll
        for (int mt = 0; mt < 4; ++mt)
#pragma unroll
            for (int nt = 0; nt < 4; ++nt) {
                int n = n0 + wn + nt * 16 + l;
#pragma unroll
                for (int r = 0; r < 4; ++r) {
                    int ch = mt * 16 + qd * 4 + r;
                    vv[((size_t)(b * NH_ + h) * CH_ + ch) * N_ + n] = f2b(acc[mt][nt][r] + bv[mt][r]);
                }
            }
    }
}

// ---------------- Kernel 3: attention; P-transpose on VALU via permlane swaps ----------------
__global__ __launch_bounds__(256, 4) void attn_kernel(const unsigned short* __restrict__ qT,
                                                      const unsigned short* __restrict__ kT,
                                                      const unsigned short* __restrict__ vv,
                                                      unsigned short* __restrict__ at)
{
    __shared__ unsigned short Ks[2][4096];   // [64 j][64 ch], 16B-block swizzled
    __shared__ unsigned short Vs[2][4096];   // [64 ch][64 j], 16B-block swizzled

    int t = threadIdx.x, lane = t & 63, wv = t >> 6;
    int l = lane & 15, qd = lane >> 4;
    int blk = blockIdx.x;
    int ibk = blk >> 7;           // i-block; bh in low bits => same (b,h) shares XCD
    int bh  = blk & 127;
    int h = bh & 7, b = bh >> 3;
    int i0 = ibk * 128 + wv * 32;
    const size_t hoff = (size_t)bh * (size_t)N_ * CH_;
    const unsigned short* qbase = qT + hoff;
    const unsigned short* kbase = kT + hoff;
    const unsigned short* vbase = vv + hoff;

    // runtime probe of permlane swap row-phase (wave-uniform). Fast path if it
    // matches the derivation; else fall back to verified shuffle transpose.
    int plok;
    {
        unsigned int ta = (unsigned int)lane, tb = 64u + (unsigned int)lane;
        asm volatile("v_permlane32_swap_b32 %0, %1" : "+v"(ta), "+v"(tb));
        asm volatile("v_permlane16_swap_b32 %0, %1" : "+v"(ta), "+v"(tb));
        unsigned int e1 = (unsigned int)((lane >> 4) * 32 + (lane & 15));
        plok = __all(ta == e1) && __all(tb == e1 + 16u);
    }

    short8 qF[2][2];
#pragma unroll
    for (int it = 0; it < 2; ++it)
#pragma unroll
        for (int ks = 0; ks < 2; ++ks)
            qF[it][ks] = *(const short8*)(qbase + (size_t)(i0 + it * 16 + l) * CH_ + ks * 32 + qd * 8);

    int srow = t >> 2, sc16 = (t & 3) * 16;
    int sw = srow & 7, bb = (t & 3) * 2;
    int d0 = srow * 64 + ((bb ^ sw) * 8);
    int d1 = srow * 64 + (((bb + 1) ^ sw) * 8);
    const unsigned short* kSrc = kbase + (size_t)srow * CH_ + sc16;
    const unsigned short* vSrc = vbase + (size_t)srow * N_ + sc16;

    f32x4 Oa[4][2] = {};
    float lsum[2] = {0.f, 0.f};
    int la0 = (qd & 1) * 32 + l;
    int la1 = la0 + 16;
    int swl = l & 7;

    uint4 ku0, ku1, vu0, vu1;
    {
        const uint4* kp = (const uint4*)(kSrc);
        ku0 = kp[0]; ku1 = kp[1];
        const uint4* vp2 = (const uint4*)(vSrc);
        vu0 = vp2[0]; vu1 = vp2[1];
        *(uint4*)&Ks[0][d0] = ku0; *(uint4*)&Ks[0][d1] = ku1;
        *(uint4*)&Vs[0][d0] = vu0; *(uint4*)&Vs[0][d1] = vu1;
        kp  = (const uint4*)(kSrc + 4096);
        ku0 = kp[0]; ku1 = kp[1];
        vp2 = (const uint4*)(vSrc + 64);
        vu0 = vp2[0]; vu1 = vp2[1];
    }

    for (int tile = 0; tile < 16; ++tile) {
        __syncthreads();
        if (tile < 15) {
            unsigned short* Kw = Ks[(tile + 1) & 1];
            unsigned short* Vw = Vs[(tile + 1) & 1];
            *(uint4*)&Kw[d0] = ku0; *(uint4*)&Kw[d1] = ku1;
            *(uint4*)&Vw[d0] = vu0; *(uint4*)&Vw[d1] = vu1;
            if (tile < 14) {
                const uint4* kp = (const uint4*)(kSrc + (size_t)(tile + 2) * 4096);
                ku0 = kp[0]; ku1 = kp[1];
                const uint4* vp2 = (const uint4*)(vSrc + (size_t)(tile + 2) * 64);
                vu0 = vp2[0]; vu1 = vp2[1];
            }
        }
        const unsigned short* Kb = Ks[tile & 1];
        const unsigned short* Vb = Vs[tile & 1];
#pragma unroll
        for (int jb = 0; jb < 2; ++jb) {
            short8 kA[2][2];
#pragma unroll
            for (int jt = 0; jt < 2; ++jt)
#pragma unroll
                for (int ks = 0; ks < 2; ++ks)
                    kA[jt][ks] = *(const short8*)&Kb[(jb * 32 + jt * 16 + l) * 64 + (((ks * 4 + qd) ^ swl) * 8)];
            f32x4 Sa[2][2] = {};
#pragma unroll
            for (int jt = 0; jt < 2; ++jt)
#pragma unroll
                for (int it = 0; it < 2; ++it)
#pragma unroll
                    for (int ks = 0; ks < 2; ++ks)
                        Sa[jt][it] = __builtin_amdgcn_mfma_f32_16x16x32_bf16(kA[jt][ks], qF[it][ks], Sa[jt][it], 0, 0, 0);
            unsigned int pk[2][2][2];
#pragma unroll
            for (int jt = 0; jt < 2; ++jt)
#pragma unroll
                for (int it = 0; it < 2; ++it) {
                    float p0 = __builtin_amdgcn_exp2f(Sa[jt][it][0]);
                    float p1 = __builtin_amdgcn_exp2f(Sa[jt][it][1]);
                    float p2 = __builtin_amdgcn_exp2f(Sa[jt][it][2]);
                    float p3 = __builtin_amdgcn_exp2f(Sa[jt][it][3]);
                    lsum[it] += (p0 + p1) + (p2 + p3);
                    pk[jt][it][0] = packtr(p0, p1);
                    pk[jt][it][1] = packtr(p2, p3);
                }
            short8 bP[2];
            if (plok) {
                // VALU transpose: 2 swaps per register pair
#pragma unroll
                for (int it = 0; it < 2; ++it) {
                    union { short8 s; unsigned int u[4]; } fb;
                    unsigned int a0 = pk[0][it][0], c0 = pk[1][it][0];
                    asm volatile("v_permlane32_swap_b32 %0, %1" : "+v"(a0), "+v"(c0));
                    asm volatile("v_permlane16_swap_b32 %0, %1" : "+v"(a0), "+v"(c0));
                    unsigned int a1 = pk[0][it][1], c1 = pk[1][it][1];
                    asm volatile("v_permlane32_swap_b32 %0, %1" : "+v"(a1), "+v"(c1));
                    asm volatile("v_permlane16_swap_b32 %0, %1" : "+v"(a1), "+v"(c1));
                    fb.u[0] = a0; fb.u[1] = a1; fb.u[2] = c0; fb.u[3] = c1;
                    bP[it] = fb.s;
                }
            } else {
                // fallback: verified shuffle transpose (R3/R5 path)
#pragma unroll
                for (int it = 0; it < 2; ++it) {
                    union { short8 s; unsigned int u[4]; } fb;
                    unsigned int a0 = (unsigned int)__shfl((int)pk[0][it][0], la0);
                    unsigned int b0 = (unsigned int)__shfl((int)pk[1][it][0], la0);
                    fb.u[0] = (qd < 2) ? a0 : b0;
                    unsigned int a1 = (unsigned int)__shfl((int)pk[0][it][1], la0);
                    unsigned int b1 = (unsigned int)__shfl((int)pk[1][it][1], la0);
                    fb.u[1] = (qd < 2) ? a1 : b1;
                    unsigned int a2 = (unsigned int)__shfl((int)pk[0][it][0], la1);
                    unsigned int b2 = (unsigned int)__shfl((int)pk[1][it][0], la1);
                    fb.u[2] = (qd < 2) ? a2 : b2;
                    unsigned int a3 = (unsigned int)__shfl((int)pk[0][it][1], la1);
                    unsigned int b3 = (unsigned int)__shfl((int)pk[1][it][1], la1);
                    fb.u[3] = (qd < 2) ? a3 : b3;
                    bP[it] = fb.s;
                }
            }
            short8 vA[4];
#pragma unroll
            for (int cht = 0; cht < 4; ++cht)
                vA[cht] = *(const short8*)&Vb[(cht * 16 + l) * 64 + (((jb * 4 + qd) ^ swl) * 8)];
#pragma unroll
            for (int cht = 0; cht < 4; ++cht)
#pragma unroll
                for (int it = 0; it < 2; ++it)
                    Oa[cht][it] = __builtin_amdgcn_mfma_f32_16x16x32_bf16(vA[cht], bP[it], Oa[cht][it], 0, 0, 0);
        }
    }

#pragma unroll
    for (int it = 0; it < 2; ++it) {
        float lt = lsum[it];
        lt += __shfl_xor(lt, 16);
        lt += __shfl_xor(lt, 32);
        float inv = 1.0f / lt;
        int i = i0 + it * 16 + l;
        unsigned short* dst = at + ((size_t)(b * N_ + i)) * C_ + h * CH_;
#pragma unroll
        for (int cht = 0; cht < 4; ++cht) {
            ushort4 o;
            o.x = f2b(Oa[cht][it][0] * inv);
            o.y = f2b(Oa[cht][it][1] * inv);
            o.z = f2b(Oa[cht][it][2] * inv);
            o.w = f2b(Oa[cht][it][3] * inv);
            *(ushort4*)(dst + cht * 16 + qd * 4) = o;
        }
    }
}

// ---------------- Kernel 4: proj GEMM, global_load_lds staging + bias + residual ----------------
__global__ __launch_bounds__(256) void proj_kernel(const unsigned short* __restrict__ w,
                                                   const float* __restrict__ bias,
                                                   const unsigned short* __restrict__ at,
                                                   const float* __restrict__ x,
                                                   float* __restrict__ out)
{
    __shared__ unsigned short Als[128 * 32], Bls[128 * 32];
    int t = threadIdx.x;
    int n0 = blockIdx.x * 128, m0 = blockIdx.y * 128, b = blockIdx.z;
    int lane = t & 63, wv = t >> 6;
    int l = lane & 15, qd = lane >> 4;
    int wm = (wv >> 1) * 64, wn = (wv & 1) * 64;
    f32x4 acc[4][4] = {};
    const unsigned short* Bbase = at + ((size_t)(b * N_ + n0)) * C_;

    int lr = lane >> 2, bpos = lane & 3;
    int r0 = wv * 32 + lr, r1 = r0 + 16;
    int c0 = (bpos ^ ((r0 >> 1) & 3)) * 8;
    int c1 = (bpos ^ ((r1 >> 1) & 3)) * 8;
    const unsigned short* gA0 = w + (size_t)(m0 + r0) * C_ + c0;
    const unsigned short* gA1 = w + (size_t)(m0 + r1) * C_ + c1;
    const unsigned short* gB0 = Bbase + (size_t)r0 * C_ + c0;
    const unsigned short* gB1 = Bbase + (size_t)r1 * C_ + c1;
    unsigned short* lA0 = &Als[(wv * 32) * 32];
    unsigned short* lA1 = &Als[(wv * 32 + 16) * 32];
    unsigned short* lB0 = &Bls[(wv * 32) * 32];
    unsigned short* lB1 = &Bls[(wv * 32 + 16) * 32];

    int aoff[4], boff[4];
#pragma unroll
    for (int i = 0; i < 4; ++i) {
        int ra = wm + i * 16 + l;
        aoff[i] = ra * 32 + ((qd ^ ((ra >> 1) & 3)) * 8);
        int rb = wn + i * 16 + l;
        boff[i] = rb * 32 + ((qd ^ ((rb >> 1) & 3)) * 8);
    }

    for (int kk = 0; kk < 16; ++kk) {
        int ko = kk * 32;
        gload16(gA0 + ko, lA0); gload16(gA1 + ko, lA1);
        gload16(gB0 + ko, lB0); gload16(gB1 + ko, lB1);
        __builtin_amdgcn_s_waitcnt(0);
        __syncthreads();
        short8 aF[4], bF[4];
#pragma unroll
        for (int i = 0; i < 4; ++i) {
            aF[i] = *(const short8*)&Als[aoff[i]];
            bF[i] = *(const short8*)&Bls[boff[i]];
        }
#pragma unroll
        for (int mt = 0; mt < 4; ++mt)
#pragma unroll
            for (int nt = 0; nt < 4; ++nt)
                acc[mt][nt] = __builtin_amdgcn_mfma_f32_16x16x32_bf16(aF[mt], bF[nt], acc[mt][nt], 0, 0, 0);
        __syncthreads();
    }

    float bv[4][4];
#pragma unroll
    for (int mt = 0; mt < 4; ++mt)
#pragma unroll
        for (int r = 0; r < 4; ++r)
            bv[mt][r] = bias[m0 + wm + mt * 16 + qd * 4 + r];

#pragma unroll
    for (int mt = 0; mt < 4; ++mt)
#pragma unroll
        for (int nt = 0; nt < 4; ++nt) {
            int n = n0 + wn + nt * 16 + l;
#pragma unroll
            for (int r = 0; r < 4; ++r) {
                int o = m0 + wm + mt * 16 + qd * 4 + r;
                size_t idx = ((size_t)b * C_ + o) * N_ + n;
                out[idx] = acc[mt][nt][r] + bv[mt][r] + x[idx];
            }
        }
}

extern "C" void kernel_launch(void* const* d_in, const int* in_sizes, int n_in,
                              void* d_out, int out_size, void* d_ws, size_t ws_size,
                              hipStream_t stream) {
    const float* x     = (const float*)d_in[0];
    const float* nw    = (const float*)d_in[1];
    const float* nb    = (const float*)d_in[2];
    const float* qkvw  = (const float*)d_in[3];
    const float* qkvb  = (const float*)d_in[4];
    const float* projw = (const float*)d_in[5];
    const float* projb = (const float*)d_in[6];
    float* out = (float*)d_out;
    char* ws = (char*)d_ws;
    const size_t SZ = (size_t)B_ * N_ * C_ * 2;   // 16 MiB per bf16 [b][n][c] tensor
    unsigned short* xnT = (unsigned short*)(ws);
    unsigned short* qTp = (unsigned short*)(ws + SZ);
    unsigned short* kTp = (unsigned short*)(ws + 2 * SZ);
    unsigned short* vp  = (unsigned short*)(ws + 3 * SZ);
    unsigned short* atp = (unsigned short*)(ws);          // alias xnT: dead after qkv_kernel
    unsigned short* wq  = (unsigned short*)(ws + 4 * SZ); // bf16 qkv_w (1.5 MiB)
    unsigned short* wp  = (unsigned short*)(ws + 4 * SZ + (size_t)3 * C_ * C_ * 2); // bf16 proj_w

    hipLaunchKernelGGL(gnconv_kernel, dim3(1024), dim3(256), 0, stream, x, nw, nb, xnT, qkvw, projw, wq, wp);
    hipLaunchKernelGGL(qkv_kernel,    dim3(8, 12, B_), dim3(256), 0, stream, wq, qkvb, xnT, qTp, kTp, vp);
    hipLaunchKernelGGL(attn_kernel,   dim3(1024), dim3(256), 0, stream, qTp, kTp, vp, atp);
    hipLaunchKernelGGL(proj_kernel,   dim3(8, 4, B_), dim3(256), 0, stream, wp, projb, atp, x, out);
}